// Round 1
// baseline (486.767 us; speedup 1.0000x reference)
//
#include <hip/hip_runtime.h>
#include <hip/hip_bf16.h>

typedef unsigned short u16;
typedef unsigned int   u32;
typedef __attribute__((ext_vector_type(8))) short bf16x8;
typedef __attribute__((ext_vector_type(4))) float f32x4;

static constexpr int kS = 128, kD = 1024, kC = 65536, kN = 512, kNNZ = 262144;

__device__ __forceinline__ u16 f2bf(float x) {
  u32 u = __float_as_uint(x);
  u32 r = (u + 0x7fffu + ((u >> 16) & 1u)) >> 16;   // RTNE
  return (u16)r;
}
__device__ __forceinline__ float bf_lo(u32 v) { return __uint_as_float(v << 16); }
__device__ __forceinline__ float bf_hi(u32 v) { return __uint_as_float(v & 0xffff0000u); }

// ---------------- 1a: BN stats over gathered rows ----------------
__global__ void k_bn_stats(const float* __restrict__ enc, const int* __restrict__ bidx,
                           const int* __restrict__ tgt, float* __restrict__ mean,
                           float* __restrict__ rstd) {
  __shared__ int offs[kN];
  for (int i = threadIdx.x; i < kN; i += blockDim.x)
    offs[i] = bidx[i] * kS + tgt[i];
  __syncthreads();
  int d = blockIdx.x * blockDim.x + threadIdx.x;   // 4 blocks x 256 = 1024 features
  float s = 0.f, ss = 0.f;
  for (int n = 0; n < kN; ++n) {
    float v = enc[(size_t)offs[n] * kD + d];
    s += v; ss += v * v;
  }
  float m = s * (1.f / kN);
  float var = ss * (1.f / kN) - m * m;             // biased var (ddof=0)
  mean[d] = m;
  rstd[d] = 1.f / sqrtf(var + 1e-5f);
}

// ---------------- 1b: h0 = (g - mean) * rstd  -> bf16 ----------------
__global__ void k_bn_apply(const float* __restrict__ enc, const int* __restrict__ bidx,
                           const int* __restrict__ tgt, const float* __restrict__ mean,
                           const float* __restrict__ rstd, u16* __restrict__ h0) {
  int i = blockIdx.x * blockDim.x + threadIdx.x;   // 512 blocks x 256 -> 131072 quads
  int n = i >> 8;
  int d = (i & 255) << 2;
  size_t src = (size_t)(bidx[n] * kS + tgt[n]) * kD + d;
  float4 v  = *(const float4*)(enc + src);
  float4 mn = *(const float4*)(mean + d);
  float4 rs = *(const float4*)(rstd + d);
  u32 q0 = (u32)f2bf((v.x - mn.x) * rs.x) | ((u32)f2bf((v.y - mn.y) * rs.y) << 16);
  u32 q1 = (u32)f2bf((v.z - mn.z) * rs.z) | ((u32)f2bf((v.w - mn.w) * rs.w) << 16);
  *(uint2*)(h0 + (size_t)n * kD + d) = make_uint2(q0, q1);
}

// ---------------- sort: histogram / scan / scatter ----------------
__global__ void k_hist(const int* __restrict__ rows, int* __restrict__ hist) {
  int e = blockIdx.x * blockDim.x + threadIdx.x;
  if (e < kNNZ) atomicAdd(&hist[rows[e]], 1);
}

__global__ __launch_bounds__(1024) void k_scan(int* __restrict__ hist, int* __restrict__ cursor) {
  __shared__ int sm[1024];
  int t = threadIdx.x;
  int base = t * 64;
  int sum = 0;
  for (int i = 0; i < 64; ++i) sum += hist[base + i];
  sm[t] = sum;
  __syncthreads();
  for (int off = 1; off < 1024; off <<= 1) {
    int v = (t >= off) ? sm[t - off] : 0;
    __syncthreads();
    sm[t] += v;
    __syncthreads();
  }
  int run = sm[t] - sum;                 // exclusive prefix for this chunk
  for (int i = 0; i < 64; ++i) {
    int v = hist[base + i];
    hist[base + i] = run;                // row_ptr
    cursor[base + i] = run;              // scatter cursor copy
    run += v;
  }
  if (t == 1023) hist[kC] = run;         // == kNNZ
}

__global__ void k_scatter(const int* __restrict__ rows, const int* __restrict__ cols,
                          const float* __restrict__ vals, int* __restrict__ cursor,
                          int* __restrict__ scol, float* __restrict__ sval) {
  int e = blockIdx.x * blockDim.x + threadIdx.x;
  if (e < kNNZ) {
    int r = rows[e];
    int p = atomicAdd(&cursor[r], 1);
    scol[p] = cols[e];
    sval[p] = vals[e];
  }
}

// ---------------- GEMM: h1t[c][n] = swish(h0[n][:] . W[c][:] + b[c]) ----------------
#define AS 72   // padded LDS row stride (bf16 units): stride-72 spreads b128 bank groups
__global__ __launch_bounds__(256)
void k_gemm(const float* __restrict__ W, const u16* __restrict__ h0,
            const float* __restrict__ bias, u16* __restrict__ h1t) {
  __shared__ __align__(16) u16 Ab[128 * AS];
  __shared__ __align__(16) u16 Bb[128 * AS];
  int t = threadIdx.x;
  int cb = blockIdx.x * 128, nb0 = blockIdx.y * 128;
  int l = t & 63, w = t >> 6;
  int wm = (w >> 1) * 64, wn = (w & 1) * 64;      // 2x2 wave grid, 64x64 per wave
  f32x4 zero = {0.f, 0.f, 0.f, 0.f};
  f32x4 acc[4][4];
#pragma unroll
  for (int a = 0; a < 4; ++a)
#pragma unroll
    for (int b = 0; b < 4; ++b) acc[a][b] = zero;

  for (int kt = 0; kt < kD; kt += 64) {
    __syncthreads();
#pragma unroll
    for (int r4 = 0; r4 < 4; ++r4) {
      int idx = r4 * 256 + t;
      int row = idx >> 3, s = idx & 7;           // 128 rows x 8 16B-slots
      // A: f32 -> bf16 reg-staged (coalesced: 8 lanes cover one 256B row chunk)
      const float4* ga = (const float4*)(W + (size_t)(cb + row) * kD + kt + s * 8);
      float4 a0 = ga[0], a1 = ga[1];
      u32 q0 = (u32)f2bf(a0.x) | ((u32)f2bf(a0.y) << 16);
      u32 q1 = (u32)f2bf(a0.z) | ((u32)f2bf(a0.w) << 16);
      u32 q2 = (u32)f2bf(a1.x) | ((u32)f2bf(a1.y) << 16);
      u32 q3 = (u32)f2bf(a1.z) | ((u32)f2bf(a1.w) << 16);
      *(uint4*)(Ab + row * AS + s * 8) = make_uint4(q0, q1, q2, q3);
      // B: h0 already bf16
      *(uint4*)(Bb + row * AS + s * 8) =
          *(const uint4*)(h0 + (size_t)(nb0 + row) * kD + kt + s * 8);
    }
    __syncthreads();
#pragma unroll
    for (int ks = 0; ks < 2; ++ks) {
      bf16x8 af[4], bv[4];
#pragma unroll
      for (int mb = 0; mb < 4; ++mb)
        af[mb] = *(const bf16x8*)(Ab + (wm + mb * 16 + (l & 15)) * AS + ks * 32 + (l >> 4) * 8);
#pragma unroll
      for (int nb = 0; nb < 4; ++nb)
        bv[nb] = *(const bf16x8*)(Bb + (wn + nb * 16 + (l & 15)) * AS + ks * 32 + (l >> 4) * 8);
#pragma unroll
      for (int mb = 0; mb < 4; ++mb)
#pragma unroll
        for (int nb = 0; nb < 4; ++nb)
          acc[mb][nb] = __builtin_amdgcn_mfma_f32_16x16x32_bf16(af[mb], bv[nb], acc[mb][nb], 0, 0, 0);
    }
  }
  // epilogue: + bias, swish, bf16 store (C/D map: col=lane&15, row=(lane>>4)*4+i)
#pragma unroll
  for (int mb = 0; mb < 4; ++mb) {
    int rb = wm + mb * 16 + (l >> 4) * 4;
#pragma unroll
    for (int i = 0; i < 4; ++i) {
      int c = cb + rb + i;
      float bvs = bias[c];
#pragma unroll
      for (int nb = 0; nb < 4; ++nb) {
        float x = acc[mb][nb][i] + bvs;
        float sw = x / (1.f + __expf(-x));
        h1t[(size_t)c * kN + (nb0 + wn + nb * 16 + (l & 15))] = f2bf(sw);
      }
    }
  }
}

// ---------------- spmm + residual + transposed write ----------------
// block: 512 thr (8 waves), 64 rows; 4 n-chunks of 128; LDS tile transposed out.
__global__ __launch_bounds__(512)
void k_spmm(const u16* __restrict__ h1t, const int* __restrict__ rowptr,
            const int* __restrict__ scol, const float* __restrict__ sval,
            float* __restrict__ out) {
  __shared__ float tile[64][129];
  int r0 = blockIdx.x * 64;
  int t = threadIdx.x;
  int w = t >> 6, l = t & 63;
  for (int ch = 0; ch < 4; ++ch) {
    int nbq = ch * 64;                    // chunk offset in u32 (bf16x2) units
#pragma unroll 1
    for (int j = 0; j < 8; ++j) {
      int rl = w * 8 + j;
      int r = r0 + rl;
      u32 hv = ((const u32*)h1t)[(size_t)r * 256 + nbq + l];
      float ax = bf_lo(hv), ay = bf_hi(hv);          // residual h1
      int e0 = rowptr[r], e1 = rowptr[r + 1];
      for (int e = e0; e < e1; ++e) {
        int c = scol[e];
        float v = sval[e];
        u32 cv = ((const u32*)h1t)[(size_t)c * 256 + nbq + l];
        ax = fmaf(v, bf_lo(cv), ax);
        ay = fmaf(v, bf_hi(cv), ay);
      }
      tile[rl][2 * l]     = ax;
      tile[rl][2 * l + 1] = ay;
    }
    __syncthreads();
#pragma unroll
    for (int it = 0; it < 16; ++it) {
      int nl = it * 8 + w;                // 0..127
      out[(size_t)(ch * 128 + nl) * kC + r0 + l] = tile[l][nl];
    }
    __syncthreads();
  }
}

extern "C" void kernel_launch(void* const* d_in, const int* in_sizes, int n_in,
                              void* d_out, int out_size, void* d_ws, size_t ws_size,
                              hipStream_t stream) {
  (void)in_sizes; (void)n_in; (void)out_size; (void)ws_size;
  const float* enc   = (const float*)d_in[0];
  const float* W     = (const float*)d_in[1];
  const float* bias  = (const float*)d_in[2];
  const float* Avals = (const float*)d_in[3];
  const int*   bidx  = (const int*)d_in[4];
  const int*   tgt   = (const int*)d_in[5];
  const int*   Arow  = (const int*)d_in[6];
  const int*   Acol  = Arow + kNNZ;
  float* out = (float*)d_out;

  char* ws = (char*)d_ws;
  float* mean   = (float*)(ws);                       //   4 KB
  float* rstd   = (float*)(ws + 4096);                //   4 KB
  u16*   h0     = (u16*)  (ws + 8192);                //   1 MB
  int*   rowptr = (int*)  (ws + 1056768);             // 256 KB (+1)
  int*   cursor = (int*)  (ws + 1319168);             // 256 KB
  int*   scol   = (int*)  (ws + 1581312);             //   1 MB
  float* sval   = (float*)(ws + 2629888);             //   1 MB
  u16*   h1t    = (u16*)  (ws + 4194304);             //  64 MB

  hipMemsetAsync(rowptr, 0, (kC + 1) * sizeof(int), stream);
  k_bn_stats<<<4, 256, 0, stream>>>(enc, bidx, tgt, mean, rstd);
  k_bn_apply<<<512, 256, 0, stream>>>(enc, bidx, tgt, mean, rstd, h0);
  k_hist<<<kNNZ / 256, 256, 0, stream>>>(Arow, rowptr);
  k_scan<<<1, 1024, 0, stream>>>(rowptr, cursor);
  k_scatter<<<kNNZ / 256, 256, 0, stream>>>(Arow, Acol, Avals, cursor, scol, sval);
  k_gemm<<<dim3(kC / 128, kN / 128), 256, 0, stream>>>(W, h0, bias, h1t);
  k_spmm<<<kC / 64, 512, 0, stream>>>(h1t, rowptr, scol, sval, out);
}

// Round 2
// 384.724 us; speedup vs baseline: 1.2652x; 1.2652x over previous
//
#include <hip/hip_runtime.h>
#include <hip/hip_bf16.h>

typedef unsigned short u16;
typedef unsigned int   u32;
typedef __attribute__((ext_vector_type(8))) short bf16x8;
typedef __attribute__((ext_vector_type(4))) float f32x4;

static constexpr int kS = 128, kD = 1024, kC = 65536, kN = 512, kNNZ = 262144;

__device__ __forceinline__ u16 f2bf(float x) {
  u32 u = __float_as_uint(x);
  u32 r = (u + 0x7fffu + ((u >> 16) & 1u)) >> 16;   // RTNE
  return (u16)r;
}
__device__ __forceinline__ float bf_lo(u32 v) { return __uint_as_float(v << 16); }
__device__ __forceinline__ float bf_hi(u32 v) { return __uint_as_float(v & 0xffff0000u); }

__device__ __forceinline__ void gload16(const void* g, void* l) {
  __builtin_amdgcn_global_load_lds(
      (const __attribute__((address_space(1))) void*)g,
      (__attribute__((address_space(3))) void*)l, 16, 0, 0);
}

// ---------------- BN stats: two-stage partial sums ----------------
__global__ void k_bn_part(const float* __restrict__ enc, const int* __restrict__ bidx,
                          const int* __restrict__ tgt, float* __restrict__ part) {
  __shared__ int offs[64];
  int n0 = blockIdx.y * 64;
  if (threadIdx.x < 64) offs[threadIdx.x] = bidx[n0 + threadIdx.x] * kS + tgt[n0 + threadIdx.x];
  __syncthreads();
  int d = blockIdx.x * 256 + threadIdx.x;
  float s = 0.f, ss = 0.f;
  for (int i = 0; i < 64; ++i) {
    float v = enc[(size_t)offs[i] * kD + d];
    s += v; ss += v * v;
  }
  part[(blockIdx.y * 2 + 0) * kD + d] = s;
  part[(blockIdx.y * 2 + 1) * kD + d] = ss;
}

__global__ void k_bn_fin(const float* __restrict__ part, float* __restrict__ mean,
                         float* __restrict__ rstd) {
  int d = blockIdx.x * 256 + threadIdx.x;
  float s = 0.f, ss = 0.f;
#pragma unroll
  for (int b = 0; b < 8; ++b) {
    s  += part[(b * 2 + 0) * kD + d];
    ss += part[(b * 2 + 1) * kD + d];
  }
  float m = s * (1.f / kN);
  float var = ss * (1.f / kN) - m * m;
  mean[d] = m;
  rstd[d] = 1.f / sqrtf(var + 1e-5f);
}

// ---------------- h0 = (g - mean) * rstd  -> bf16 ----------------
__global__ void k_bn_apply(const float* __restrict__ enc, const int* __restrict__ bidx,
                           const int* __restrict__ tgt, const float* __restrict__ mean,
                           const float* __restrict__ rstd, u16* __restrict__ h0) {
  int i = blockIdx.x * blockDim.x + threadIdx.x;
  int n = i >> 8;
  int d = (i & 255) << 2;
  size_t src = (size_t)(bidx[n] * kS + tgt[n]) * kD + d;
  float4 v  = *(const float4*)(enc + src);
  float4 mn = *(const float4*)(mean + d);
  float4 rs = *(const float4*)(rstd + d);
  u32 q0 = (u32)f2bf((v.x - mn.x) * rs.x) | ((u32)f2bf((v.y - mn.y) * rs.y) << 16);
  u32 q1 = (u32)f2bf((v.z - mn.z) * rs.z) | ((u32)f2bf((v.w - mn.w) * rs.w) << 16);
  *(uint2*)(h0 + (size_t)n * kD + d) = make_uint2(q0, q1);
}

// ---------------- W f32 -> bf16 streaming convert ----------------
__global__ __launch_bounds__(256)
void k_conv(const float* __restrict__ W, u16* __restrict__ Wb) {
  size_t i = (size_t)(blockIdx.x * 256 + threadIdx.x) * 8;
  const size_t stride = (size_t)2048 * 256 * 8;
  const size_t total = (size_t)kC * kD;
  for (; i < total; i += stride) {
    float4 v0 = *(const float4*)(W + i);
    float4 v1 = *(const float4*)(W + i + 4);
    u32 q0 = (u32)f2bf(v0.x) | ((u32)f2bf(v0.y) << 16);
    u32 q1 = (u32)f2bf(v0.z) | ((u32)f2bf(v0.w) << 16);
    u32 q2 = (u32)f2bf(v1.x) | ((u32)f2bf(v1.y) << 16);
    u32 q3 = (u32)f2bf(v1.z) | ((u32)f2bf(v1.w) << 16);
    *(uint4*)(Wb + i) = make_uint4(q0, q1, q2, q3);
  }
}

// ---------------- sort: histogram / scan / scatter ----------------
__global__ void k_hist(const int* __restrict__ rows, int* __restrict__ hist) {
  int e = blockIdx.x * blockDim.x + threadIdx.x;
  if (e < kNNZ) atomicAdd(&hist[rows[e]], 1);
}

__global__ __launch_bounds__(1024) void k_scan(int* __restrict__ hist, int* __restrict__ cursor) {
  __shared__ int sm[1024];
  int t = threadIdx.x;
  int base = t * 64;
  int sum = 0;
  for (int i = 0; i < 64; ++i) sum += hist[base + i];
  sm[t] = sum;
  __syncthreads();
  for (int off = 1; off < 1024; off <<= 1) {
    int v = (t >= off) ? sm[t - off] : 0;
    __syncthreads();
    sm[t] += v;
    __syncthreads();
  }
  int run = sm[t] - sum;
  for (int i = 0; i < 64; ++i) {
    int v = hist[base + i];
    hist[base + i] = run;
    cursor[base + i] = run;
    run += v;
  }
  if (t == 1023) hist[kC] = run;
}

__global__ void k_scatter(const int* __restrict__ rows, const int* __restrict__ cols,
                          const float* __restrict__ vals, int* __restrict__ cursor,
                          int* __restrict__ scol, float* __restrict__ sval) {
  int e = blockIdx.x * blockDim.x + threadIdx.x;
  if (e < kNNZ) {
    int r = rows[e];
    int p = atomicAdd(&cursor[r], 1);
    scol[p] = cols[e];
    sval[p] = vals[e];
  }
}

// ---------------- GEMM v2 (m97 structure): bf16 W, global_load_lds both operands ----------------
__global__ __launch_bounds__(256)
void k_gemm2(const u16* __restrict__ Wb, const u16* __restrict__ h0,
             const float* __restrict__ bias, u16* __restrict__ h1t) {
  __shared__ __align__(16) u16 Ab[128 * 64];
  __shared__ __align__(16) u16 Bb[128 * 64];
  int t = threadIdx.x;
  int cb = blockIdx.x * 128, nb0 = blockIdx.y * 128;
  int l = t & 63, w = t >> 6;
  int wm = (w >> 1) * 64, wn = (w & 1) * 64;
  f32x4 zero = {0.f, 0.f, 0.f, 0.f};
  f32x4 acc[4][4];
#pragma unroll
  for (int a = 0; a < 4; ++a)
#pragma unroll
    for (int b = 0; b < 4; ++b) acc[a][b] = zero;

  for (int kt = 0; kt < kD; kt += 64) {
    __syncthreads();
#pragma unroll
    for (int i = 0; i < 4; ++i) {
      int s = i * 256 + t;                  // 1024 16B slots = 128 rows x 8
      int row = s >> 3, ko = (s & 7) * 8;
      gload16(Wb + (size_t)(cb + row) * kD + kt + ko, Ab + s * 8);
      gload16(h0 + (size_t)(nb0 + row) * kD + kt + ko, Bb + s * 8);
    }
    __syncthreads();                        // compiler drains vmcnt(0) here
#pragma unroll
    for (int ks = 0; ks < 2; ++ks) {
      bf16x8 af[4], bv[4];
#pragma unroll
      for (int mb = 0; mb < 4; ++mb)
        af[mb] = *(const bf16x8*)(Ab + (wm + mb * 16 + (l & 15)) * 64 + ks * 32 + (l >> 4) * 8);
#pragma unroll
      for (int nb = 0; nb < 4; ++nb)
        bv[nb] = *(const bf16x8*)(Bb + (wn + nb * 16 + (l & 15)) * 64 + ks * 32 + (l >> 4) * 8);
#pragma unroll
      for (int mb = 0; mb < 4; ++mb)
#pragma unroll
        for (int nb = 0; nb < 4; ++nb)
          acc[mb][nb] = __builtin_amdgcn_mfma_f32_16x16x32_bf16(af[mb], bv[nb], acc[mb][nb], 0, 0, 0);
    }
  }
#pragma unroll
  for (int mb = 0; mb < 4; ++mb) {
    int rb = wm + mb * 16 + (l >> 4) * 4;
#pragma unroll
    for (int i = 0; i < 4; ++i) {
      int c = cb + rb + i;
      float bvs = bias[c];
#pragma unroll
      for (int nb = 0; nb < 4; ++nb) {
        float x = acc[mb][nb][i] + bvs;
        float sw = x / (1.f + __expf(-x));
        h1t[(size_t)c * kN + (nb0 + wn + nb * 16 + (l & 15))] = f2bf(sw);
      }
    }
  }
}

// ---------------- GEMM fallback (R1, in-loop convert) if ws too small ----------------
#define AS 72
__global__ __launch_bounds__(256)
void k_gemm_fb(const float* __restrict__ W, const u16* __restrict__ h0,
               const float* __restrict__ bias, u16* __restrict__ h1t) {
  __shared__ __align__(16) u16 Ab[128 * AS];
  __shared__ __align__(16) u16 Bb[128 * AS];
  int t = threadIdx.x;
  int cb = blockIdx.x * 128, nb0 = blockIdx.y * 128;
  int l = t & 63, w = t >> 6;
  int wm = (w >> 1) * 64, wn = (w & 1) * 64;
  f32x4 zero = {0.f, 0.f, 0.f, 0.f};
  f32x4 acc[4][4];
#pragma unroll
  for (int a = 0; a < 4; ++a)
#pragma unroll
    for (int b = 0; b < 4; ++b) acc[a][b] = zero;
  for (int kt = 0; kt < kD; kt += 64) {
    __syncthreads();
#pragma unroll
    for (int r4 = 0; r4 < 4; ++r4) {
      int idx = r4 * 256 + t;
      int row = idx >> 3, s = idx & 7;
      const float4* ga = (const float4*)(W + (size_t)(cb + row) * kD + kt + s * 8);
      float4 a0 = ga[0], a1 = ga[1];
      u32 q0 = (u32)f2bf(a0.x) | ((u32)f2bf(a0.y) << 16);
      u32 q1 = (u32)f2bf(a0.z) | ((u32)f2bf(a0.w) << 16);
      u32 q2 = (u32)f2bf(a1.x) | ((u32)f2bf(a1.y) << 16);
      u32 q3 = (u32)f2bf(a1.z) | ((u32)f2bf(a1.w) << 16);
      *(uint4*)(Ab + row * AS + s * 8) = make_uint4(q0, q1, q2, q3);
      *(uint4*)(Bb + row * AS + s * 8) =
          *(const uint4*)(h0 + (size_t)(nb0 + row) * kD + kt + s * 8);
    }
    __syncthreads();
#pragma unroll
    for (int ks = 0; ks < 2; ++ks) {
      bf16x8 af[4], bv[4];
#pragma unroll
      for (int mb = 0; mb < 4; ++mb)
        af[mb] = *(const bf16x8*)(Ab + (wm + mb * 16 + (l & 15)) * AS + ks * 32 + (l >> 4) * 8);
#pragma unroll
      for (int nb = 0; nb < 4; ++nb)
        bv[nb] = *(const bf16x8*)(Bb + (wn + nb * 16 + (l & 15)) * AS + ks * 32 + (l >> 4) * 8);
#pragma unroll
      for (int mb = 0; mb < 4; ++mb)
#pragma unroll
        for (int nb = 0; nb < 4; ++nb)
          acc[mb][nb] = __builtin_amdgcn_mfma_f32_16x16x32_bf16(af[mb], bv[nb], acc[mb][nb], 0, 0, 0);
    }
  }
#pragma unroll
  for (int mb = 0; mb < 4; ++mb) {
    int rb = wm + mb * 16 + (l >> 4) * 4;
#pragma unroll
    for (int i = 0; i < 4; ++i) {
      int c = cb + rb + i;
      float bvs = bias[c];
#pragma unroll
      for (int nb = 0; nb < 4; ++nb) {
        float x = acc[mb][nb][i] + bvs;
        float sw = x / (1.f + __expf(-x));
        h1t[(size_t)c * kN + (nb0 + wn + nb * 16 + (l & 15))] = f2bf(sw);
      }
    }
  }
}

// ---------------- spmm: 32 rows/block, full N per edge, dwordx4 gathers ----------------
__global__ __launch_bounds__(512)
void k_spmm(const u16* __restrict__ h1t, const int* __restrict__ rowptr,
            const int* __restrict__ scol, const float* __restrict__ sval,
            float* __restrict__ out) {
  __shared__ float tile[32 * 512];   // XOR-swizzled, 64 KB
  int r0 = blockIdx.x * 32;
  int t = threadIdx.x, w = t >> 6, l = t & 63;
#pragma unroll
  for (int j = 0; j < 4; ++j) {
    int rl = w * 4 + j;
    int r = r0 + rl;
    uint4 hv = ((const uint4*)(h1t + (size_t)r * kN))[l];
    float a0 = bf_lo(hv.x), a1 = bf_hi(hv.x), a2 = bf_lo(hv.y), a3 = bf_hi(hv.y);
    float a4 = bf_lo(hv.z), a5 = bf_hi(hv.z), a6 = bf_lo(hv.w), a7 = bf_hi(hv.w);
    int e0 = rowptr[r], e1 = rowptr[r + 1];
    int c = 0; float v = 0.f;
    if (e0 < e1) { c = scol[e0]; v = sval[e0]; }
    for (int e = e0; e < e1; ++e) {
      uint4 cv = ((const uint4*)(h1t + (size_t)c * kN))[l];
      int cn = 0; float vn = 0.f;
      if (e + 1 < e1) { cn = scol[e + 1]; vn = sval[e + 1]; }   // prefetch
      a0 = fmaf(v, bf_lo(cv.x), a0); a1 = fmaf(v, bf_hi(cv.x), a1);
      a2 = fmaf(v, bf_lo(cv.y), a2); a3 = fmaf(v, bf_hi(cv.y), a3);
      a4 = fmaf(v, bf_lo(cv.z), a4); a5 = fmaf(v, bf_hi(cv.z), a5);
      a6 = fmaf(v, bf_lo(cv.w), a6); a7 = fmaf(v, bf_hi(cv.w), a7);
      c = cn; v = vn;
    }
    int sw = (rl & 7) << 2;          // XOR bits 2..4 keep float4 groups intact
    *(float4*)&tile[rl * 512 + ((8 * l) ^ sw)]     = make_float4(a0, a1, a2, a3);
    *(float4*)&tile[rl * 512 + ((8 * l + 4) ^ sw)] = make_float4(a4, a5, a6, a7);
  }
  __syncthreads();
  int r = l & 31;
  int swr = (r & 7) << 2;
#pragma unroll
  for (int it = 0; it < 32; ++it) {
    int n = it * 16 + w * 2 + (l >> 5);
    out[(size_t)n * kC + r0 + r] = tile[r * 512 + (n ^ swr)];
  }
}

extern "C" void kernel_launch(void* const* d_in, const int* in_sizes, int n_in,
                              void* d_out, int out_size, void* d_ws, size_t ws_size,
                              hipStream_t stream) {
  (void)in_sizes; (void)n_in; (void)out_size;
  const float* enc   = (const float*)d_in[0];
  const float* W     = (const float*)d_in[1];
  const float* bias  = (const float*)d_in[2];
  const float* Avals = (const float*)d_in[3];
  const int*   bidx  = (const int*)d_in[4];
  const int*   tgt   = (const int*)d_in[5];
  const int*   Arow  = (const int*)d_in[6];
  const int*   Acol  = Arow + kNNZ;
  float* out = (float*)d_out;

  char* ws = (char*)d_ws;
  float* mean   = (float*)(ws);                       //   4 KB
  float* rstd   = (float*)(ws + 4096);                //   4 KB
  u16*   h0     = (u16*)  (ws + 8192);                //   1 MB
  int*   rowptr = (int*)  (ws + 1056768);             // 256 KB (+1)
  int*   cursor = (int*)  (ws + 1319168);             // 256 KB
  int*   scol   = (int*)  (ws + 1581312);             //   1 MB
  float* sval   = (float*)(ws + 2629888);             //   1 MB
  float* part   = (float*)(ws + 3678464);             //  64 KB
  u16*   h1t    = (u16*)  (ws + 4194304);             //  64 MB
  u16*   Wb     = (u16*)  (ws + 71303168);            // 128 MB
  bool bigws = ws_size >= 205520896ULL;               // 196 MB

  hipMemsetAsync(rowptr, 0, (kC + 1) * sizeof(int), stream);
  k_bn_part<<<dim3(4, 8), 256, 0, stream>>>(enc, bidx, tgt, part);
  k_bn_fin<<<4, 256, 0, stream>>>(part, mean, rstd);
  k_bn_apply<<<512, 256, 0, stream>>>(enc, bidx, tgt, mean, rstd, h0);
  k_hist<<<kNNZ / 256, 256, 0, stream>>>(Arow, rowptr);
  k_scan<<<1, 1024, 0, stream>>>(rowptr, cursor);
  k_scatter<<<kNNZ / 256, 256, 0, stream>>>(Arow, Acol, Avals, cursor, scol, sval);
  if (bigws) {
    k_conv<<<2048, 256, 0, stream>>>(W, Wb);
    k_gemm2<<<dim3(kC / 128, kN / 128), 256, 0, stream>>>(Wb, h0, bias, h1t);
  } else {
    k_gemm_fb<<<dim3(kC / 128, kN / 128), 256, 0, stream>>>(W, h0, bias, h1t);
  }
  k_spmm<<<kC / 32, 512, 0, stream>>>(h1t, rowptr, scol, sval, out);
}

// Round 3
// 294.879 us; speedup vs baseline: 1.6507x; 1.3047x over previous
//
#include <hip/hip_runtime.h>
#include <hip/hip_bf16.h>

typedef unsigned short u16;
typedef unsigned int   u32;
typedef __attribute__((ext_vector_type(8))) short bf16x8;
typedef __attribute__((ext_vector_type(4))) float f32x4;

static constexpr int kS = 128, kD = 1024, kC = 65536, kN = 512, kNNZ = 262144;

__device__ __forceinline__ u16 f2bf(float x) {
  u32 u = __float_as_uint(x);
  u32 r = (u + 0x7fffu + ((u >> 16) & 1u)) >> 16;   // RTNE
  return (u16)r;
}
__device__ __forceinline__ u32 pack2(float a, float b) {
  return (u32)f2bf(a) | ((u32)f2bf(b) << 16);
}
__device__ __forceinline__ float bf_lo(u32 v) { return __uint_as_float(v << 16); }
__device__ __forceinline__ float bf_hi(u32 v) { return __uint_as_float(v & 0xffff0000u); }

// ---------------- BN stats: two-stage partial sums ----------------
__global__ void k_bn_part(const float* __restrict__ enc, const int* __restrict__ bidx,
                          const int* __restrict__ tgt, float* __restrict__ part) {
  __shared__ int offs[64];
  int n0 = blockIdx.y * 64;
  if (threadIdx.x < 64) offs[threadIdx.x] = bidx[n0 + threadIdx.x] * kS + tgt[n0 + threadIdx.x];
  __syncthreads();
  int d = blockIdx.x * 256 + threadIdx.x;
  float s = 0.f, ss = 0.f;
  for (int i = 0; i < 64; ++i) {
    float v = enc[(size_t)offs[i] * kD + d];
    s += v; ss += v * v;
  }
  part[(blockIdx.y * 2 + 0) * kD + d] = s;
  part[(blockIdx.y * 2 + 1) * kD + d] = ss;
}

__global__ void k_bn_fin(const float* __restrict__ part, float* __restrict__ mean,
                         float* __restrict__ rstd) {
  int d = blockIdx.x * 256 + threadIdx.x;
  float s = 0.f, ss = 0.f;
#pragma unroll
  for (int b = 0; b < 8; ++b) {
    s  += part[(b * 2 + 0) * kD + d];
    ss += part[(b * 2 + 1) * kD + d];
  }
  float m = s * (1.f / kN);
  float var = ss * (1.f / kN) - m * m;
  mean[d] = m;
  rstd[d] = 1.f / sqrtf(var + 1e-5f);
}

// ---------------- h0 = (g - mean) * rstd  -> bf16 ----------------
__global__ void k_bn_apply(const float* __restrict__ enc, const int* __restrict__ bidx,
                           const int* __restrict__ tgt, const float* __restrict__ mean,
                           const float* __restrict__ rstd, u16* __restrict__ h0) {
  int i = blockIdx.x * blockDim.x + threadIdx.x;
  int n = i >> 8;
  int d = (i & 255) << 2;
  size_t src = (size_t)(bidx[n] * kS + tgt[n]) * kD + d;
  float4 v  = *(const float4*)(enc + src);
  float4 mn = *(const float4*)(mean + d);
  float4 rs = *(const float4*)(rstd + d);
  u32 q0 = pack2((v.x - mn.x) * rs.x, (v.y - mn.y) * rs.y);
  u32 q1 = pack2((v.z - mn.z) * rs.z, (v.w - mn.w) * rs.w);
  *(uint2*)(h0 + (size_t)n * kD + d) = make_uint2(q0, q1);
}

// ---------------- sort: histogram / scan / scatter ----------------
__global__ void k_hist(const int* __restrict__ rows, int* __restrict__ hist) {
  int e = blockIdx.x * blockDim.x + threadIdx.x;
  if (e < kNNZ) atomicAdd(&hist[rows[e]], 1);
}

__global__ __launch_bounds__(1024) void k_scan(int* __restrict__ hist, int* __restrict__ cursor) {
  __shared__ int sm[1024];
  int t = threadIdx.x;
  int base = t * 64;
  int sum = 0;
  for (int i = 0; i < 64; ++i) sum += hist[base + i];
  sm[t] = sum;
  __syncthreads();
  for (int off = 1; off < 1024; off <<= 1) {
    int v = (t >= off) ? sm[t - off] : 0;
    __syncthreads();
    sm[t] += v;
    __syncthreads();
  }
  int run = sm[t] - sum;
  for (int i = 0; i < 64; ++i) {
    int v = hist[base + i];
    hist[base + i] = run;
    cursor[base + i] = run;
    run += v;
  }
  if (t == 1023) hist[kC] = run;
}

__global__ void k_scatter(const int* __restrict__ rows, const int* __restrict__ cols,
                          const float* __restrict__ vals, int* __restrict__ cursor,
                          int* __restrict__ scol, float* __restrict__ sval) {
  int e = blockIdx.x * blockDim.x + threadIdx.x;
  if (e < kNNZ) {
    int r = rows[e];
    int p = atomicAdd(&cursor[r], 1);
    scol[p] = cols[e];
    sval[p] = vals[e];
  }
}

// ---------------- fused GEMM: W f32 read once, convert in-reg, BM=128 x BN=512 ----------------
// 512 thr (8 waves, 2M x 4N), BK=32, single-buffer LDS 50 KB, stride 80 B (pad).
// Pipeline: [cvt+ds_write t] [issue glb loads t+1] lgkm(0) barrier [MFMA t] lgkm(0) barrier.
__global__ __launch_bounds__(512)
void k_gemm_f(const float* __restrict__ W, const u16* __restrict__ h0,
              const float* __restrict__ bias, u16* __restrict__ h1t) {
  __shared__ __align__(16) u16 Ab[128 * 40];   // [128 rows][32 k] bf16, stride 40 u16 = 80 B
  __shared__ __align__(16) u16 Bb[512 * 40];   // [512 rows][32 k]
  const int t = threadIdx.x;
  const int l = t & 63, w = t >> 6;
  const int wm = (w >> 2) * 64, wn = (w & 3) * 128;
  const int cb = blockIdx.x * 128;

  // A staging map: slots g = t, t+512; row = g>>3 (0..127), q = g&7 (float4 within 32 f32)
  const int ar = t >> 3, aq = t & 7;
  // B staging map: slots s = t + 512*i (i=0..3); row = s>>2 (0..511), q = s&3 (16B within 64 B)
  const int br = t >> 2, bq = t & 3;

  const float* gA0 = W + (size_t)(cb + ar) * kD + aq * 4;
  const float* gA1 = W + (size_t)(cb + ar + 64) * kD + aq * 4;
  const u16*   gB  = h0 + (size_t)br * kD + bq * 8;

  char* Abc = (char*)Ab;
  char* Bbc = (char*)Bb;
  u32 aw0 = ar * 80 + aq * 8, aw1 = (ar + 64) * 80 + aq * 8;
  u32 bw = br * 80 + bq * 16;

  f32x4 acc[4][8];
#pragma unroll
  for (int a = 0; a < 4; ++a)
#pragma unroll
    for (int b = 0; b < 8; ++b) acc[a][b] = (f32x4){0.f, 0.f, 0.f, 0.f};

  // prologue: prefetch kt=0 into registers
  float4 nA0 = *(const float4*)gA0;
  float4 nA1 = *(const float4*)gA1;
  uint4 nB0 = *(const uint4*)(gB);
  uint4 nB1 = *(const uint4*)(gB + 128 * kD);
  uint4 nB2 = *(const uint4*)(gB + 256 * kD);
  uint4 nB3 = *(const uint4*)(gB + 384 * kD);

#pragma unroll 1
  for (int it = 0; it < 32; ++it) {
    // ---- write phase: LDS tile for iter `it` (prev barrier guarantees LDS free) ----
    *(uint2*)(Abc + aw0) = make_uint2(pack2(nA0.x, nA0.y), pack2(nA0.z, nA0.w));
    *(uint2*)(Abc + aw1) = make_uint2(pack2(nA1.x, nA1.y), pack2(nA1.z, nA1.w));
    *(uint4*)(Bbc + bw)  = nB0;
    *(uint4*)(Bbc + bw + 128 * 80) = nB1;
    *(uint4*)(Bbc + bw + 256 * 80) = nB2;
    *(uint4*)(Bbc + bw + 384 * 80) = nB3;
    // ---- issue next-tile global loads (in flight across MFMA phase) ----
    int ktn = (it < 31) ? (it + 1) * 32 : 0;
    nA0 = *(const float4*)(gA0 + ktn);
    nA1 = *(const float4*)(gA1 + ktn);
    nB0 = *(const uint4*)(gB + ktn);
    nB1 = *(const uint4*)(gB + 128 * kD + ktn);
    nB2 = *(const uint4*)(gB + 256 * kD + ktn);
    nB3 = *(const uint4*)(gB + 384 * kD + ktn);
    // ---- writes visible to all waves ----
    asm volatile("s_waitcnt lgkmcnt(0)" ::: "memory");
    __builtin_amdgcn_s_barrier();
    __builtin_amdgcn_sched_barrier(0);
    // ---- MFMA phase ----
    bf16x8 af[4], bv[8];
#pragma unroll
    for (int mb = 0; mb < 4; ++mb)
      af[mb] = *(const bf16x8*)(Abc + (wm + mb * 16 + (l & 15)) * 80 + (l >> 4) * 16);
#pragma unroll
    for (int nb = 0; nb < 8; ++nb)
      bv[nb] = *(const bf16x8*)(Bbc + (wn + nb * 16 + (l & 15)) * 80 + (l >> 4) * 16);
#pragma unroll
    for (int mb = 0; mb < 4; ++mb)
#pragma unroll
      for (int nb = 0; nb < 8; ++nb)
        acc[mb][nb] = __builtin_amdgcn_mfma_f32_16x16x32_bf16(af[mb], bv[nb], acc[mb][nb], 0, 0, 0);
    // ---- all reads retired before next overwrite ----
    asm volatile("s_waitcnt lgkmcnt(0)" ::: "memory");
    __builtin_amdgcn_s_barrier();
    __builtin_amdgcn_sched_barrier(0);
  }

  // epilogue: + bias, swish, bf16 store (C/D map: col=lane&15, row=(lane>>4)*4+i)
#pragma unroll
  for (int mb = 0; mb < 4; ++mb) {
    int rb = wm + mb * 16 + (l >> 4) * 4;
#pragma unroll
    for (int i = 0; i < 4; ++i) {
      int c = cb + rb + i;
      float bvs = bias[c];
#pragma unroll
      for (int nb = 0; nb < 8; ++nb) {
        float x = acc[mb][nb][i] + bvs;
        float sw = x / (1.f + __expf(-x));
        h1t[(size_t)c * kN + (wn + nb * 16 + (l & 15))] = f2bf(sw);
      }
    }
  }
}

// ---------------- spmm: 32 rows/block, full N per edge, dwordx4 gathers ----------------
__global__ __launch_bounds__(512)
void k_spmm(const u16* __restrict__ h1t, const int* __restrict__ rowptr,
            const int* __restrict__ scol, const float* __restrict__ sval,
            float* __restrict__ out) {
  __shared__ float tile[32 * 512];   // XOR-swizzled, 64 KB
  int r0 = blockIdx.x * 32;
  int t = threadIdx.x, w = t >> 6, l = t & 63;
#pragma unroll
  for (int j = 0; j < 4; ++j) {
    int rl = w * 4 + j;
    int r = r0 + rl;
    uint4 hv = ((const uint4*)(h1t + (size_t)r * kN))[l];
    float a0 = bf_lo(hv.x), a1 = bf_hi(hv.x), a2 = bf_lo(hv.y), a3 = bf_hi(hv.y);
    float a4 = bf_lo(hv.z), a5 = bf_hi(hv.z), a6 = bf_lo(hv.w), a7 = bf_hi(hv.w);
    int e0 = rowptr[r], e1 = rowptr[r + 1];
    int c = 0; float v = 0.f;
    if (e0 < e1) { c = scol[e0]; v = sval[e0]; }
    for (int e = e0; e < e1; ++e) {
      uint4 cv = ((const uint4*)(h1t + (size_t)c * kN))[l];
      int cn = 0; float vn = 0.f;
      if (e + 1 < e1) { cn = scol[e + 1]; vn = sval[e + 1]; }   // prefetch
      a0 = fmaf(v, bf_lo(cv.x), a0); a1 = fmaf(v, bf_hi(cv.x), a1);
      a2 = fmaf(v, bf_lo(cv.y), a2); a3 = fmaf(v, bf_hi(cv.y), a3);
      a4 = fmaf(v, bf_lo(cv.z), a4); a5 = fmaf(v, bf_hi(cv.z), a5);
      a6 = fmaf(v, bf_lo(cv.w), a6); a7 = fmaf(v, bf_hi(cv.w), a7);
      c = cn; v = vn;
    }
    int sw = (rl & 7) << 2;          // XOR bits 2..4 keep float4 groups intact
    *(float4*)&tile[rl * 512 + ((8 * l) ^ sw)]     = make_float4(a0, a1, a2, a3);
    *(float4*)&tile[rl * 512 + ((8 * l + 4) ^ sw)] = make_float4(a4, a5, a6, a7);
  }
  __syncthreads();
  int r = l & 31;
  int swr = (r & 7) << 2;
#pragma unroll
  for (int it = 0; it < 32; ++it) {
    int n = it * 16 + w * 2 + (l >> 5);
    out[(size_t)n * kC + r0 + r] = tile[r * 512 + (n ^ swr)];
  }
}

extern "C" void kernel_launch(void* const* d_in, const int* in_sizes, int n_in,
                              void* d_out, int out_size, void* d_ws, size_t ws_size,
                              hipStream_t stream) {
  (void)in_sizes; (void)n_in; (void)out_size; (void)ws_size;
  const float* enc   = (const float*)d_in[0];
  const float* W     = (const float*)d_in[1];
  const float* bias  = (const float*)d_in[2];
  const float* Avals = (const float*)d_in[3];
  const int*   bidx  = (const int*)d_in[4];
  const int*   tgt   = (const int*)d_in[5];
  const int*   Arow  = (const int*)d_in[6];
  const int*   Acol  = Arow + kNNZ;
  float* out = (float*)d_out;

  char* ws = (char*)d_ws;
  float* mean   = (float*)(ws);                       //   4 KB
  float* rstd   = (float*)(ws + 4096);                //   4 KB
  u16*   h0     = (u16*)  (ws + 8192);                //   1 MB
  int*   rowptr = (int*)  (ws + 1056768);             // 256 KB (+1)
  int*   cursor = (int*)  (ws + 1319168);             // 256 KB
  int*   scol   = (int*)  (ws + 1581312);             //   1 MB
  float* sval   = (float*)(ws + 2629888);             //   1 MB
  float* part   = (float*)(ws + 3678464);             //  64 KB
  u16*   h1t    = (u16*)  (ws + 4194304);             //  64 MB

  hipMemsetAsync(rowptr, 0, (kC + 1) * sizeof(int), stream);
  k_bn_part<<<dim3(4, 8), 256, 0, stream>>>(enc, bidx, tgt, part);
  k_bn_fin<<<4, 256, 0, stream>>>(part, mean, rstd);
  k_bn_apply<<<512, 256, 0, stream>>>(enc, bidx, tgt, mean, rstd, h0);
  k_hist<<<kNNZ / 256, 256, 0, stream>>>(Arow, rowptr);
  k_scan<<<1, 1024, 0, stream>>>(rowptr, cursor);
  k_scatter<<<kNNZ / 256, 256, 0, stream>>>(Arow, Acol, Avals, cursor, scol, sval);
  k_gemm_f<<<kC / 128, 512, 0, stream>>>(W, h0, bias, h1t);
  k_spmm<<<kC / 32, 512, 0, stream>>>(h1t, rowptr, scol, sval, out);
}

// Round 4
// 292.635 us; speedup vs baseline: 1.6634x; 1.0077x over previous
//
#include <hip/hip_runtime.h>
#include <hip/hip_bf16.h>

typedef unsigned short u16;
typedef unsigned int   u32;
typedef __attribute__((ext_vector_type(8))) short bf16x8;
typedef __attribute__((ext_vector_type(4))) float f32x4;

static constexpr int kS = 128, kD = 1024, kC = 65536, kN = 512, kNNZ = 262144;

__device__ __forceinline__ u16 f2bf(float x) {
  u32 u = __float_as_uint(x);
  u32 r = (u + 0x7fffu + ((u >> 16) & 1u)) >> 16;   // RTNE
  return (u16)r;
}
__device__ __forceinline__ u32 pack2(float a, float b) {
  return (u32)f2bf(a) | ((u32)f2bf(b) << 16);
}
__device__ __forceinline__ float bf_lo(u32 v) { return __uint_as_float(v << 16); }
__device__ __forceinline__ float bf_hi(u32 v) { return __uint_as_float(v & 0xffff0000u); }

// ---------------- BN stats: two-stage partial sums ----------------
__global__ void k_bn_part(const float* __restrict__ enc, const int* __restrict__ bidx,
                          const int* __restrict__ tgt, float* __restrict__ part) {
  __shared__ int offs[64];
  int n0 = blockIdx.y * 64;
  if (threadIdx.x < 64) offs[threadIdx.x] = bidx[n0 + threadIdx.x] * kS + tgt[n0 + threadIdx.x];
  __syncthreads();
  int d = blockIdx.x * 256 + threadIdx.x;
  float s = 0.f, ss = 0.f;
  for (int i = 0; i < 64; ++i) {
    float v = enc[(size_t)offs[i] * kD + d];
    s += v; ss += v * v;
  }
  part[(blockIdx.y * 2 + 0) * kD + d] = s;
  part[(blockIdx.y * 2 + 1) * kD + d] = ss;
}

__global__ void k_bn_fin(const float* __restrict__ part, float* __restrict__ mean,
                         float* __restrict__ rstd) {
  int d = blockIdx.x * 256 + threadIdx.x;
  float s = 0.f, ss = 0.f;
#pragma unroll
  for (int b = 0; b < 8; ++b) {
    s  += part[(b * 2 + 0) * kD + d];
    ss += part[(b * 2 + 1) * kD + d];
  }
  float m = s * (1.f / kN);
  float var = ss * (1.f / kN) - m * m;
  mean[d] = m;
  rstd[d] = 1.f / sqrtf(var + 1e-5f);
}

// ---------------- h0 = (g - mean) * rstd  -> bf16 ----------------
__global__ void k_bn_apply(const float* __restrict__ enc, const int* __restrict__ bidx,
                           const int* __restrict__ tgt, const float* __restrict__ mean,
                           const float* __restrict__ rstd, u16* __restrict__ h0) {
  int i = blockIdx.x * blockDim.x + threadIdx.x;
  int n = i >> 8;
  int d = (i & 255) << 2;
  size_t src = (size_t)(bidx[n] * kS + tgt[n]) * kD + d;
  float4 v  = *(const float4*)(enc + src);
  float4 mn = *(const float4*)(mean + d);
  float4 rs = *(const float4*)(rstd + d);
  u32 q0 = pack2((v.x - mn.x) * rs.x, (v.y - mn.y) * rs.y);
  u32 q1 = pack2((v.z - mn.z) * rs.z, (v.w - mn.w) * rs.w);
  *(uint2*)(h0 + (size_t)n * kD + d) = make_uint2(q0, q1);
}

// ---------------- sort: histogram / scan / scatter ----------------
__global__ void k_hist(const int* __restrict__ rows, int* __restrict__ hist) {
  int e = blockIdx.x * blockDim.x + threadIdx.x;
  if (e < kNNZ) atomicAdd(&hist[rows[e]], 1);
}

__global__ __launch_bounds__(1024) void k_scan(int* __restrict__ hist, int* __restrict__ cursor) {
  __shared__ int sm[1024];
  int t = threadIdx.x;
  int base = t * 64;
  int sum = 0;
  for (int i = 0; i < 64; ++i) sum += hist[base + i];
  sm[t] = sum;
  __syncthreads();
  for (int off = 1; off < 1024; off <<= 1) {
    int v = (t >= off) ? sm[t - off] : 0;
    __syncthreads();
    sm[t] += v;
    __syncthreads();
  }
  int run = sm[t] - sum;
  for (int i = 0; i < 64; ++i) {
    int v = hist[base + i];
    hist[base + i] = run;
    cursor[base + i] = run;
    run += v;
  }
  if (t == 1023) hist[kC] = run;
}

__global__ void k_scatter(const int* __restrict__ rows, const int* __restrict__ cols,
                          const float* __restrict__ vals, int* __restrict__ cursor,
                          int* __restrict__ scol, float* __restrict__ sval) {
  int e = blockIdx.x * blockDim.x + threadIdx.x;
  if (e < kNNZ) {
    int r = rows[e];
    int p = atomicAdd(&cursor[r], 1);
    scol[p] = cols[e];
    sval[p] = vals[e];
  }
}

// ---------------- fused GEMM: W f32 read once, convert in-reg, BM=128 x BN=512 ----------------
// 512 thr (8 waves, 2M x 4N), BK=32, single-buffer LDS 50 KB, stride 80 B (pad).
// Pipeline: [cvt+ds_write t] [issue glb loads t+1] lgkm(0) barrier [MFMA t] lgkm(0) barrier.
__global__ __launch_bounds__(512)
void k_gemm_f(const float* __restrict__ W, const u16* __restrict__ h0,
              const float* __restrict__ bias, u16* __restrict__ h1t) {
  __shared__ __align__(16) u16 Ab[128 * 40];   // [128 rows][32 k] bf16, stride 40 u16 = 80 B
  __shared__ __align__(16) u16 Bb[512 * 40];   // [512 rows][32 k]
  const int t = threadIdx.x;
  const int l = t & 63, w = t >> 6;
  const int wm = (w >> 2) * 64, wn = (w & 3) * 128;
  const int cb = blockIdx.x * 128;

  // A staging map: slots g = t, t+512; row = g>>3 (0..127), q = g&7 (float4 within 32 f32)
  const int ar = t >> 3, aq = t & 7;
  // B staging map: slots s = t + 512*i (i=0..3); row = s>>2 (0..511), q = s&3 (16B within 64 B)
  const int br = t >> 2, bq = t & 3;

  const float* gA0 = W + (size_t)(cb + ar) * kD + aq * 4;
  const float* gA1 = W + (size_t)(cb + ar + 64) * kD + aq * 4;
  const u16*   gB  = h0 + (size_t)br * kD + bq * 8;

  char* Abc = (char*)Ab;
  char* Bbc = (char*)Bb;
  u32 aw0 = ar * 80 + aq * 8, aw1 = (ar + 64) * 80 + aq * 8;
  u32 bw = br * 80 + bq * 16;

  f32x4 acc[4][8];
#pragma unroll
  for (int a = 0; a < 4; ++a)
#pragma unroll
    for (int b = 0; b < 8; ++b) acc[a][b] = (f32x4){0.f, 0.f, 0.f, 0.f};

  // prologue: prefetch kt=0 into registers
  float4 nA0 = *(const float4*)gA0;
  float4 nA1 = *(const float4*)gA1;
  uint4 nB0 = *(const uint4*)(gB);
  uint4 nB1 = *(const uint4*)(gB + 128 * kD);
  uint4 nB2 = *(const uint4*)(gB + 256 * kD);
  uint4 nB3 = *(const uint4*)(gB + 384 * kD);

#pragma unroll 1
  for (int it = 0; it < 32; ++it) {
    // ---- write phase: LDS tile for iter `it` (prev barrier guarantees LDS free) ----
    *(uint2*)(Abc + aw0) = make_uint2(pack2(nA0.x, nA0.y), pack2(nA0.z, nA0.w));
    *(uint2*)(Abc + aw1) = make_uint2(pack2(nA1.x, nA1.y), pack2(nA1.z, nA1.w));
    *(uint4*)(Bbc + bw)  = nB0;
    *(uint4*)(Bbc + bw + 128 * 80) = nB1;
    *(uint4*)(Bbc + bw + 256 * 80) = nB2;
    *(uint4*)(Bbc + bw + 384 * 80) = nB3;
    // ---- issue next-tile global loads (in flight across MFMA phase) ----
    int ktn = (it < 31) ? (it + 1) * 32 : 0;
    nA0 = *(const float4*)(gA0 + ktn);
    nA1 = *(const float4*)(gA1 + ktn);
    nB0 = *(const uint4*)(gB + ktn);
    nB1 = *(const uint4*)(gB + 128 * kD + ktn);
    nB2 = *(const uint4*)(gB + 256 * kD + ktn);
    nB3 = *(const uint4*)(gB + 384 * kD + ktn);
    // ---- writes visible to all waves ----
    asm volatile("s_waitcnt lgkmcnt(0)" ::: "memory");
    __builtin_amdgcn_s_barrier();
    __builtin_amdgcn_sched_barrier(0);
    // ---- MFMA phase ----
    bf16x8 af[4], bv[8];
#pragma unroll
    for (int mb = 0; mb < 4; ++mb)
      af[mb] = *(const bf16x8*)(Abc + (wm + mb * 16 + (l & 15)) * 80 + (l >> 4) * 16);
#pragma unroll
    for (int nb = 0; nb < 8; ++nb)
      bv[nb] = *(const bf16x8*)(Bbc + (wn + nb * 16 + (l & 15)) * 80 + (l >> 4) * 16);
#pragma unroll
    for (int mb = 0; mb < 4; ++mb)
#pragma unroll
      for (int nb = 0; nb < 8; ++nb)
        acc[mb][nb] = __builtin_amdgcn_mfma_f32_16x16x32_bf16(af[mb], bv[nb], acc[mb][nb], 0, 0, 0);
    // ---- all reads retired before next overwrite ----
    asm volatile("s_waitcnt lgkmcnt(0)" ::: "memory");
    __builtin_amdgcn_s_barrier();
    __builtin_amdgcn_sched_barrier(0);
  }

  // epilogue: + bias, swish, bf16 store (C/D map: col=lane&15, row=(lane>>4)*4+i)
#pragma unroll
  for (int mb = 0; mb < 4; ++mb) {
    int rb = wm + mb * 16 + (l >> 4) * 4;
#pragma unroll
    for (int i = 0; i < 4; ++i) {
      int c = cb + rb + i;
      float bvs = bias[c];
#pragma unroll
      for (int nb = 0; nb < 8; ++nb) {
        float x = acc[mb][nb][i] + bvs;
        float sw = x / (1.f + __expf(-x));
        h1t[(size_t)c * kN + (wn + nb * 16 + (l & 15))] = f2bf(sw);
      }
    }
  }
}

// ---------------- spmm: 32 rows/block, full N per edge, dwordx4 gathers ----------------
__global__ __launch_bounds__(512)
void k_spmm(const u16* __restrict__ h1t, const int* __restrict__ rowptr,
            const int* __restrict__ scol, const float* __restrict__ sval,
            float* __restrict__ out) {
  __shared__ float tile[32 * 512];   // XOR-swizzled, 64 KB
  int r0 = blockIdx.x * 32;
  int t = threadIdx.x, w = t >> 6, l = t & 63;
#pragma unroll
  for (int j = 0; j < 4; ++j) {
    int rl = w * 4 + j;
    int r = r0 + rl;
    uint4 hv = ((const uint4*)(h1t + (size_t)r * kN))[l];
    float a0 = bf_lo(hv.x), a1 = bf_hi(hv.x), a2 = bf_lo(hv.y), a3 = bf_hi(hv.y);
    float a4 = bf_lo(hv.z), a5 = bf_hi(hv.z), a6 = bf_lo(hv.w), a7 = bf_hi(hv.w);
    int e0 = rowptr[r], e1 = rowptr[r + 1];
    int c = 0; float v = 0.f;
    if (e0 < e1) { c = scol[e0]; v = sval[e0]; }
    for (int e = e0; e < e1; ++e) {
      uint4 cv = ((const uint4*)(h1t + (size_t)c * kN))[l];
      int cn = 0; float vn = 0.f;
      if (e + 1 < e1) { cn = scol[e + 1]; vn = sval[e + 1]; }   // prefetch
      a0 = fmaf(v, bf_lo(cv.x), a0); a1 = fmaf(v, bf_hi(cv.x), a1);
      a2 = fmaf(v, bf_lo(cv.y), a2); a3 = fmaf(v, bf_hi(cv.y), a3);
      a4 = fmaf(v, bf_lo(cv.z), a4); a5 = fmaf(v, bf_hi(cv.z), a5);
      a6 = fmaf(v, bf_lo(cv.w), a6); a7 = fmaf(v, bf_hi(cv.w), a7);
      c = cn; v = vn;
    }
    int sw = (rl & 7) << 2;          // XOR bits 2..4 keep float4 groups intact
    *(float4*)&tile[rl * 512 + ((8 * l) ^ sw)]     = make_float4(a0, a1, a2, a3);
    *(float4*)&tile[rl * 512 + ((8 * l + 4) ^ sw)] = make_float4(a4, a5, a6, a7);
  }
  __syncthreads();
  int r = l & 31;
  int swr = (r & 7) << 2;
#pragma unroll
  for (int it = 0; it < 32; ++it) {
    int n = it * 16 + w * 2 + (l >> 5);
    out[(size_t)n * kC + r0 + r] = tile[r * 512 + (n ^ swr)];
  }
}

extern "C" void kernel_launch(void* const* d_in, const int* in_sizes, int n_in,
                              void* d_out, int out_size, void* d_ws, size_t ws_size,
                              hipStream_t stream) {
  (void)in_sizes; (void)n_in; (void)out_size; (void)ws_size;
  const float* enc   = (const float*)d_in[0];
  const float* W     = (const float*)d_in[1];
  const float* bias  = (const float*)d_in[2];
  const float* Avals = (const float*)d_in[3];
  const int*   bidx  = (const int*)d_in[4];
  const int*   tgt   = (const int*)d_in[5];
  const int*   Arow  = (const int*)d_in[6];
  const int*   Acol  = Arow + kNNZ;
  float* out = (float*)d_out;

  char* ws = (char*)d_ws;
  float* mean   = (float*)(ws);                       //   4 KB
  float* rstd   = (float*)(ws + 4096);                //   4 KB
  u16*   h0     = (u16*)  (ws + 8192);                //   1 MB
  int*   rowptr = (int*)  (ws + 1056768);             // 256 KB (+1)
  int*   cursor = (int*)  (ws + 1319168);             // 256 KB
  int*   scol   = (int*)  (ws + 1581312);             //   1 MB
  float* sval   = (float*)(ws + 2629888);             //   1 MB
  float* part   = (float*)(ws + 3678464);             //  64 KB
  u16*   h1t    = (u16*)  (ws + 4194304);             //  64 MB

  hipMemsetAsync(rowptr, 0, (kC + 1) * sizeof(int), stream);
  k_bn_part<<<dim3(4, 8), 256, 0, stream>>>(enc, bidx, tgt, part);
  k_bn_fin<<<4, 256, 0, stream>>>(part, mean, rstd);
  k_bn_apply<<<512, 256, 0, stream>>>(enc, bidx, tgt, mean, rstd, h0);
  k_hist<<<kNNZ / 256, 256, 0, stream>>>(Arow, rowptr);
  k_scan<<<1, 1024, 0, stream>>>(rowptr, cursor);
  k_scatter<<<kNNZ / 256, 256, 0, stream>>>(Arow, Acol, Avals, cursor, scol, sval);
  k_gemm_f<<<kC / 128, 512, 0, stream>>>(W, h0, bias, h1t);
  k_spmm<<<kC / 32, 512, 0, stream>>>(h1t, rowptr, scol, sval, out);
}